// Round 5
// baseline (144.379 us; speedup 1.0000x reference)
//
#include <hip/hip_runtime.h>

// NGF loss: g = normalized gradient (central diff interior, one-sided at edges),
// loss = 1 - mean( (g0 . g1)^2 ).  B=64, C=1, H=512, W=512, fp32.
//
// R5: register sliding-window row-walker. One wave owns a full 512-col row
// (lane l -> cols [8l,8l+8), two float4); walks 16 rows with a 3-row register
// window, prefetching row h+2 while computing row h. Each row is loaded from
// global exactly once (vs 1.75x in R1); W-halos are intra-wave __shfl + image-
// edge register clamps -> zero LDS data path, zero halo loads. 4 independent
// prefetch loads/step with no same-iteration use => 4KB in flight per wave,
// 32KB per CU (8 waves/CU) >> ~9KB Little's-law need at 6.3 TB/s.

#define HH 512
#define WW 512
#define NGF_EPS 1e-10f
#define RPT 16   // rows walked per wave

__device__ __forceinline__ float rcp_fast(float x) { return __builtin_amdgcn_rcpf(x); }

// waves = 64 imgs * (512/RPT = 32 chunks) = 2048 -> 512 blocks x 256 threads
__global__ __launch_bounds__(256) void ngf_partial(const float* __restrict__ I0,
                                                   const float* __restrict__ I1,
                                                   float* __restrict__ partials) {
    const int tid  = threadIdx.x;
    const int wv   = tid >> 6;
    const int lane = tid & 63;
    const int gw   = blockIdx.x * 4 + wv;   // global wave id, 0..2047
    const int img  = gw >> 5;               // 0..63
    const int ck   = gw & 31;               // row-chunk 0..31
    const int h0   = ck * RPT;

    const float* p0 = I0 + (size_t)img * (HH * WW) + lane * 8;
    const float* p1 = I1 + (size_t)img * (HH * WW) + lane * 8;

    // 3-row window (u = h-1 clamped, c = h, n = h+1) + prefetch m = h+2.
    float4 u0a, u0b, u1a, u1b, c0a, c0b, c1a, c1b, n0a, n0b, n1a, n1b;
    {
        const int ru = (h0 > 0) ? (h0 - 1) * WW : 0;
        const int rc = h0 * WW;
        const int rn = (h0 + 1) * WW;       // h0 <= 496 -> always valid
        u0a = *(const float4*)(p0 + ru);     u0b = *(const float4*)(p0 + ru + 4);
        u1a = *(const float4*)(p1 + ru);     u1b = *(const float4*)(p1 + ru + 4);
        c0a = *(const float4*)(p0 + rc);     c0b = *(const float4*)(p0 + rc + 4);
        c1a = *(const float4*)(p1 + rc);     c1b = *(const float4*)(p1 + rc + 4);
        n0a = *(const float4*)(p0 + rn);     n0b = *(const float4*)(p0 + rn + 4);
        n1a = *(const float4*)(p1 + rn);     n1b = *(const float4*)(p1 + rn + 4);
    }

    float s = 0.f;
#pragma unroll
    for (int i = 0; i < RPT; ++i) {
        const int h  = h0 + i;
        const int hm = (h + 2 < HH) ? h + 2 : HH - 1;     // prefetch row, clamped
        const int rm = hm * WW;
        const float4 m0a = *(const float4*)(p0 + rm);
        const float4 m0b = *(const float4*)(p0 + rm + 4);
        const float4 m1a = *(const float4*)(p1 + rm);
        const float4 m1b = *(const float4*)(p1 + rm + 4);

        // W-halos from neighbors' center-row registers; image edges clamp.
        float L0 = __shfl_up(c0b.w, 1, 64);   if (lane == 0)  L0 = c0a.x;
        float R0 = __shfl_down(c0a.x, 1, 64); if (lane == 63) R0 = c0b.w;
        float L1 = __shfl_up(c1b.w, 1, 64);   if (lane == 0)  L1 = c1a.x;
        float R1 = __shfl_down(c1a.x, 1, 64); if (lane == 63) R1 = c1b.w;

        const float a0[10] = {L0, c0a.x, c0a.y, c0a.z, c0a.w,
                                  c0b.x, c0b.y, c0b.z, c0b.w, R0};
        const float a1[10] = {L1, c1a.x, c1a.y, c1a.z, c1a.w,
                                  c1b.x, c1b.y, c1b.z, c1b.w, R1};
        const float gx0[8] = {n0a.x - u0a.x, n0a.y - u0a.y, n0a.z - u0a.z, n0a.w - u0a.w,
                              n0b.x - u0b.x, n0b.y - u0b.y, n0b.z - u0b.z, n0b.w - u0b.w};
        const float gx1[8] = {n1a.x - u1a.x, n1a.y - u1a.y, n1a.z - u1a.z, n1a.w - u1a.w,
                              n1b.x - u1b.x, n1b.y - u1b.y, n1b.z - u1b.z, n1b.w - u1b.w};
#pragma unroll
        for (int j = 0; j < 8; ++j) {
            const float gy0 = a0[j + 2] - a0[j];
            const float gy1 = a1[j + 2] - a1[j];
            const float q0  = gx0[j] * gx0[j] + gy0 * gy0 + NGF_EPS;
            const float q1  = gx1[j] * gx1[j] + gy1 * gy1 + NGF_EPS;
            const float cr  = gx0[j] * gx1[j] + gy0 * gy1;
            s += cr * cr * rcp_fast(q0 * q1);   // dot^2 = cross^2/(n0*n1)
        }
        // rotate window (pure register renaming under full unroll)
        u0a = c0a; u0b = c0b; u1a = c1a; u1b = c1b;
        c0a = n0a; c0b = n0b; c1a = n1a; c1b = n1b;
        n0a = m0a; n0b = m0b; n1a = m1a; n1b = m1b;
    }

    // wave64 reduce; lane 0 writes this wave's partial directly (no LDS).
#pragma unroll
    for (int off = 32; off > 0; off >>= 1) s += __shfl_down(s, off, 64);
    if (lane == 0) partials[gw] = s;
}

// 2048 partials: 512 threads x float4, one block.
__global__ __launch_bounds__(512) void ngf_finalize(const float4* __restrict__ partials,
                                                    float inv_n,
                                                    float* __restrict__ out) {
    const float4 v = partials[threadIdx.x];
    float s = v.x + v.y + v.z + v.w;
#pragma unroll
    for (int off = 32; off > 0; off >>= 1) s += __shfl_down(s, off, 64);

    __shared__ float lds[8];
    const int wave = threadIdx.x >> 6;
    const int lane = threadIdx.x & 63;
    if (lane == 0) lds[wave] = s;
    __syncthreads();
    if (threadIdx.x == 0) {
        float tot = 0.f;
#pragma unroll
        for (int i = 0; i < 8; ++i) tot += lds[i];
        out[0] = 1.0f - tot * inv_n;
    }
}

extern "C" void kernel_launch(void* const* d_in, const int* in_sizes, int n_in,
                              void* d_out, int out_size, void* d_ws, size_t ws_size,
                              hipStream_t stream) {
    const float* I0 = (const float*)d_in[0];
    const float* I1 = (const float*)d_in[1];
    float* partials = (float*)d_ws;          // 2048 floats = 8 KB

    const int N = in_sizes[0];               // 16,777,216
    ngf_partial<<<512, 256, 0, stream>>>(I0, I1, partials);
    ngf_finalize<<<1, 512, 0, stream>>>((const float4*)partials,
                                        1.0f / (float)N, (float*)d_out);
}